// Round 3
// baseline (699.458 us; speedup 1.0000x reference)
//
#include <hip/hip_runtime.h>

#define NH 128

// ---------------------------------------------------------------------------
// K1: setup — block 0: exclusive scan of grid_sizes -> c[0..G]
//             block 1: A = Wk@Wi (LDS), u = Wk@bi, then
//                      Bt[f*NH+d] = sum_e Wi[e,d]*A[e,f]; v = Wi^T u;
//                      w[f] = bi.A[:,f]; s0 = bi.u + bk
// ---------------------------------------------------------------------------
__global__ __launch_bounds__(1024)
void setup_kernel(const int* __restrict__ gs, int* __restrict__ c, int G,
                  const float* __restrict__ Wk, const float* __restrict__ Wi,
                  const float* __restrict__ bi, const float* __restrict__ bk,
                  float* __restrict__ Bt, float* __restrict__ v,
                  float* __restrict__ w, float* __restrict__ s0) {
    if (blockIdx.x == 0) {
        __shared__ int part[1024];
        int t = threadIdx.x;
        int chunk = (G + 1023) >> 10;
        int b = t * chunk;
        int e = min(b + chunk, G);
        int s = 0;
        for (int i = b; i < e; ++i) s += gs[i];
        part[t] = s;
        __syncthreads();
        for (int off = 1; off < 1024; off <<= 1) {
            int val = (t >= off) ? part[t - off] : 0;
            __syncthreads();
            part[t] += val;
            __syncthreads();
        }
        int excl = (t == 0) ? 0 : part[t - 1];
        for (int i = b; i < e; ++i) { c[i] = excl; excl += gs[i]; }
        if (t == 1023) c[G] = part[1023];
    } else {
        __shared__ float A_s[NH * NH];     // 64 KB
        __shared__ float u_s[NH];
        int t = threadIdx.x;
        for (int idx = t; idx < NH * NH; idx += 1024) {
            int e = idx >> 7, d = idx & (NH - 1);
            float acc = 0.f;
            for (int f = 0; f < NH; ++f) acc += Wk[e * NH + f] * Wi[f * NH + d];
            A_s[idx] = acc;
        }
        if (t < NH) {
            float s = 0.f;
            for (int f = 0; f < NH; ++f) s += Wk[t * NH + f] * bi[f];
            u_s[t] = s;
        }
        __syncthreads();
        for (int idx = t; idx < NH * NH; idx += 1024) {
            int i = idx & (NH - 1), j = idx >> 7;
            float acc = 0.f;
            for (int e = 0; e < NH; ++e) acc += Wi[e * NH + i] * A_s[e * NH + j];
            Bt[j * NH + i] = acc;
        }
        if (t < NH) {
            float s = 0.f;
            for (int e = 0; e < NH; ++e) s += Wi[e * NH + t] * u_s[e];
            v[t] = s;
        } else if (t < 2 * NH) {
            int jj = t - NH;
            float s = 0.f;
            for (int e = 0; e < NH; ++e) s += bi[e] * A_s[e * NH + jj];
            w[jj] = s;
        } else if (t == 2 * NH) {
            float s = 0.f;
            for (int e = 0; e < NH; ++e) s += bi[e] * u_s[e];
            s0[0] = s + bk[0];
        }
    }
}

// ---------------------------------------------------------------------------
// K2: segq — ONE 64-LANE WAVE PER SEGMENT, no LDS, no barriers.
//     Phase a: mean of emb_ pos rows into registers (lane owns cols 2l,2l+1),
//              writes segid[r]=g.
//     Phase b: Q[g] = B.m + v via shfl-broadcast of m[f] + L2-resident Bt;
//              C2[g] = w.m + s0 via wave reduce.  (M never materialized)
// ---------------------------------------------------------------------------
#define MCH 8
__global__ __launch_bounds__(256)
void segq_kernel(const float* __restrict__ emb_, const int* __restrict__ pos,
                 const int* __restrict__ c, const float* __restrict__ Bt,
                 const float* __restrict__ v, const float* __restrict__ w,
                 const float* __restrict__ s0, float* __restrict__ Q,
                 float* __restrict__ C2, int* __restrict__ segid, int G) {
    int wave  = (blockIdx.x * blockDim.x + threadIdx.x) >> 6;
    int lane  = threadIdx.x & 63;
    int nwave = (gridDim.x * blockDim.x) >> 6;
    const float2* Bt2 = (const float2*)Bt;

    for (int g = wave; g < G; g += nwave) {
        int pb = c[g], pe = c[g + 1];
        int np = pe - pb;

        // ---- phase a: segment mean ----
        float2 acc = make_float2(0.f, 0.f);
        for (int r0 = 0; r0 < np; r0 += 64) {
            int nr = min(64, np - r0);
            int idxv = 0;
            if (lane < nr) {
                idxv = pos[pb + r0 + lane];
                segid[pb + r0 + lane] = g;
            }
            int r = 0;
            for (; r + MCH <= nr; r += MCH) {
                float2 a[MCH];
#pragma unroll
                for (int j = 0; j < MCH; ++j) {
                    int row = __shfl(idxv, r + j, 64);
                    a[j] = ((const float2*)(emb_ + (size_t)row * NH))[lane];
                }
#pragma unroll
                for (int j = 0; j < MCH; ++j) { acc.x += a[j].x; acc.y += a[j].y; }
            }
            for (; r < nr; ++r) {
                int row = __shfl(idxv, r, 64);
                float2 a = ((const float2*)(emb_ + (size_t)row * NH))[lane];
                acc.x += a.x; acc.y += a.y;
            }
        }
        float cnt = (float)max(np, 1);
        float mx = acc.x / cnt, my = acc.y / cnt;

        // ---- phase b: Q[g] = B.m + v ; C2[g] = w.m + s0 ----
        float qx = 0.f, qy = 0.f;
#pragma unroll 8
        for (int j = 0; j < 64; ++j) {
            float mf0 = __shfl(mx, j, 64);
            float mf1 = __shfl(my, j, 64);
            float2 b0 = Bt2[(2 * j)     * 64 + lane];
            float2 b1 = Bt2[(2 * j + 1) * 64 + lane];
            qx += b0.x * mf0 + b1.x * mf1;
            qy += b0.y * mf0 + b1.y * mf1;
        }
        float2 vv = ((const float2*)v)[lane];
        ((float2*)(Q + (size_t)g * NH))[lane] = make_float2(qx + vv.x, qy + vv.y);

        float2 ww = ((const float2*)w)[lane];
        float cv = ww.x * mx + ww.y * my;
#pragma unroll
        for (int off = 32; off; off >>= 1) cv += __shfl_xor(cv, off, 64);
        if (lane == 0) C2[g] = cv + s0[0];
    }
}

// ---------------------------------------------------------------------------
// K3: logits — FLAT grid-stride, 32-lane group per sample, U=4 unroll,
//     no LDS, no barriers. sid from segid[] (pos) or segid[jn/ratio] (neg,
//     via 2^42 magic division).  out[k] = emb[row].Q[sid] + C2[sid]
// ---------------------------------------------------------------------------
#define U 4
__global__ __launch_bounds__(256, 6)
void logits_kernel(const float* __restrict__ emb, const int* __restrict__ pos,
                   const int* __restrict__ neg, const int* __restrict__ segid,
                   const float* __restrict__ Q, const float* __restrict__ C2,
                   float* __restrict__ out, int P, int PN,
                   unsigned long long magic) {
    int tot = P + PN;
    int gid  = (blockIdx.x * blockDim.x + threadIdx.x) >> 5;
    int lane = threadIdx.x & 31;
    int ngrp = (gridDim.x * blockDim.x) >> 5;
    long long stride = (long long)ngrp * U;

    for (long long base = (long long)gid * U; base < tot; base += stride) {
        int kk[U], row[U], sid[U];
#pragma unroll
        for (int j = 0; j < U; ++j) {
            int k = (int)base + j;
            int k2 = (k < tot) ? k : (tot - 1);
            kk[j] = k2;
            if (k2 < P) {
                row[j] = pos[k2];
                sid[j] = segid[k2];
            } else {
                int jn = k2 - P;
                row[j] = neg[jn];
                int jp = (int)(((unsigned long long)(unsigned)jn * magic) >> 42);
                sid[j] = segid[jp];
            }
        }
        float4 a[U], q[U];
        float c2v[U];
#pragma unroll
        for (int j = 0; j < U; ++j) {
            a[j]   = ((const float4*)(emb + (size_t)row[j] * NH))[lane];
            q[j]   = ((const float4*)(Q   + (size_t)sid[j] * NH))[lane];
            c2v[j] = C2[sid[j]];
        }
#pragma unroll
        for (int j = 0; j < U; ++j) {
            float val = a[j].x * q[j].x + a[j].y * q[j].y
                      + a[j].z * q[j].z + a[j].w * q[j].w;
#pragma unroll
            for (int off = 16; off; off >>= 1) val += __shfl_xor(val, off, 32);
            if (lane == 0 && base + j < tot) out[kk[j]] = val + c2v[j];
        }
    }
}

// ---------------------------------------------------------------------------
extern "C" void kernel_launch(void* const* d_in, const int* in_sizes, int n_in,
                              void* d_out, int out_size, void* d_ws, size_t ws_size,
                              hipStream_t stream) {
    const float* embedding  = (const float*)d_in[0];
    const float* embedding_ = (const float*)d_in[1];
    const int*   grid_sizes = (const int*)d_in[2];
    const int*   pos        = (const int*)d_in[3];
    const int*   neg        = (const int*)d_in[4];
    const float* Wi         = (const float*)d_in[5];
    const float* bi         = (const float*)d_in[6];
    const float* Wk         = (const float*)d_in[7];
    const float* bk         = (const float*)d_in[8];

    int G = in_sizes[2];
    int P = in_sizes[3];
    int PN = in_sizes[4];
    int ratio = (P > 0) ? (PN / P) : 1;
    if (ratio < 1) ratio = 1;
    unsigned long long magic = (((unsigned long long)1 << 42) + ratio - 1) / (unsigned long long)ratio;

    char* ws = (char*)d_ws;
    size_t off = 0;
    auto alloc = [&](size_t bytes) {
        void* p = ws + off;
        off += (bytes + 255) & ~(size_t)255;
        return p;
    };
    int*   c     = (int*)  alloc((size_t)(G + 1) * sizeof(int));
    float* Bt    = (float*)alloc(NH * NH * sizeof(float));
    float* v     = (float*)alloc(NH * sizeof(float));
    float* w     = (float*)alloc(NH * sizeof(float));
    float* s0    = (float*)alloc(sizeof(float));
    float* Q     = (float*)alloc((size_t)G * NH * sizeof(float));
    float* C2    = (float*)alloc((size_t)G * sizeof(float));
    int*   segid = (int*)  alloc((size_t)P * sizeof(int));
    (void)ws_size; (void)n_in; (void)out_size;

    // K1: scan (block 0) + weight algebra (block 1)
    hipLaunchKernelGGL(setup_kernel, dim3(2), dim3(1024), 0, stream,
                       grid_sizes, c, G, Wk, Wi, bi, bk, Bt, v, w, s0);
    // K2: wave-per-segment mean + Q + C2 + segid
    int sqblocks = (G + 3) / 4;
    hipLaunchKernelGGL(segq_kernel, dim3(sqblocks), dim3(256), 0, stream,
                       embedding_, pos, c, Bt, v, w, s0, Q, C2, segid, G);
    // K3: flat logits
    hipLaunchKernelGGL(logits_kernel, dim3(2048), dim3(256), 0, stream,
                       embedding, pos, neg, segid, Q, C2, (float*)d_out, P, PN, magic);
}